// Round 6
// baseline (92.872 us; speedup 1.0000x reference)
//
#include <hip/hip_runtime.h>
#include <hip/hip_bf16.h>

// Problem constants
#define B_    8
#define QLEN  2048
#define D_    1024
#define H_    16
#define KV_   256
#define HD_   64

typedef float fvec4 __attribute__((ext_vector_type(4)));

// ws layout (float offsets):
#define WS_KVEC 0        // B x 1024
#define WS_VVEC 8192     // B x 1024
#define WS_C2   16384    // B
#define WS_SW1  16392    // 1
#define WS_L    16400    // 256K floats: L[b,h,q]

__device__ inline float wave_sum(float v) {
#pragma unroll
  for (int off = 32; off > 0; off >>= 1) v += __shfl_xor(v, off, 64);
  return v;
}
__device__ inline float wave_max(float v) {
#pragma unroll
  for (int off = 32; off > 0; off >>= 1) v = fmaxf(v, __shfl_xor(v, off, 64));
  return v;
}
__device__ inline float wave_min(float v) {
#pragma unroll
  for (int off = 32; off > 0; off >>= 1) v = fminf(v, __shfl_xor(v, off, 64));
  return v;
}
template <int N>
__device__ inline void multi_sum(float* v) {
#pragma unroll
  for (int off = 32; off > 0; off >>= 1) {
#pragma unroll
    for (int r = 0; r < N; ++r) v[r] += __shfl_xor(v[r], off, 64);
  }
}

// Kernel 1: Kvec/Vvec GEMVs (weights read once; loop over b) + c2 + sw1.
// Blocks 0..127: 4 waves, wave = (sel, 4-row d-group), loops b=0..7.
// Block 128: wave 0 computes sw1 + c2.
__global__ __launch_bounds__(256) void prep_kernel(
    const float* __restrict__ key, const float* __restrict__ value,
    const float* __restrict__ kw, const float* __restrict__ vw,
    const float* __restrict__ clip, const float* __restrict__ scale_w,
    float* __restrict__ ws) {
  const int lane = threadIdx.x & 63;
  const int waveId = threadIdx.x >> 6;

  if (blockIdx.x == 128) {
    if (waveId != 0) return;
    const fvec4* sw4 = reinterpret_cast<const fvec4*>(scale_w);
    fvec4 a = sw4[lane];                       // scale_w[0..255]
    float s = wave_sum(a.x + a.y + a.z + a.w);
    if (lane == 0) ws[WS_SW1] = s;
    fvec4 w2 = sw4[64 + lane];                 // scale_w[256..511]
    for (int b = 0; b < B_; ++b) {
      const fvec4* c4 = reinterpret_cast<const fvec4*>(clip + b * KV_);
      fvec4 c = c4[lane];
      float p = c.x * w2.x + c.y * w2.y + c.z * w2.z + c.w * w2.w;
      p = wave_sum(p);
      if (lane == 0) ws[WS_C2 + b] = p;
    }
    return;
  }

  const int W = blockIdx.x * 4 + waveId;  // 0..511
  const int sel = W >> 8;                 // 0=K, 1=V
  const int g = W & 255;                  // 4-row d-group
  const float* Wt = sel ? vw : kw;
  const float* xsrc = sel ? value : key;
  float* outv = ws + (sel ? WS_VVEC : WS_KVEC);

  // Keep 4 weight rows resident: 16 fvec4 = 64 VGPR.
  fvec4 wr[4][4];
#pragma unroll
  for (int r = 0; r < 4; ++r) {
    const fvec4* w4 = reinterpret_cast<const fvec4*>(Wt + (size_t)(g * 4 + r) * 1024);
#pragma unroll
    for (int i = 0; i < 4; ++i) wr[r][i] = w4[i * 64 + lane];
  }

  for (int b = 0; b < B_; ++b) {
    const fvec4* x4 = reinterpret_cast<const fvec4*>(xsrc + b * 1024);
    fvec4 xs[4];
#pragma unroll
    for (int i = 0; i < 4; ++i) xs[i] = x4[i * 64 + lane];
    float acc[4];
#pragma unroll
    for (int r = 0; r < 4; ++r) {
      acc[r] = 0.f;
#pragma unroll
      for (int i = 0; i < 4; ++i) {
        acc[r] += xs[i].x * wr[r][i].x + xs[i].y * wr[r][i].y +
                  xs[i].z * wr[r][i].z + xs[i].w * wr[r][i].w;
      }
    }
    multi_sum<4>(acc);
    if (lane < 4) {
      const float v = (lane == 0) ? acc[0] : (lane == 1) ? acc[1]
                    : (lane == 2) ? acc[2] : acc[3];
      outv[b * 1024 + g * 4 + lane] = v;
    }
  }
}

// Kernel 2 (role-split): blocks 0..1023 stream out[b,q,:] = Vvec[b,:];
// blocks 1024..5119 compute L[row] = sw1*dot(Q_row,Kvec_head)/8 + c2[b] + sb.
__global__ __launch_bounds__(256) void qdot_out_kernel(
    const float* __restrict__ query, const float* __restrict__ scale_b,
    float* __restrict__ ws, float* __restrict__ out) {
  const int lane = threadIdx.x & 63;

  if (blockIdx.x < 1024) {
    // out broadcast: 4,194,304 float4; 1024 blocks x 256 threads x 16.
    const fvec4* v4 = reinterpret_cast<const fvec4*>(ws + WS_VVEC);
    fvec4* o4 = reinterpret_cast<fvec4*>(out);
    const int idx = blockIdx.x * 256 + threadIdx.x;   // 0..262143
#pragma unroll
    for (int i = 0; i < 16; ++i) {
      const int j = idx + i * 262144;
      const int ob = j >> 19;                          // 524288 float4 per b
      const int d4 = j & 255;
      fvec4 v = v4[ob * 256 + d4];
      __builtin_nontemporal_store(v, &o4[j]);
    }
    return;
  }

  const int waveId = threadIdx.x >> 6;
  const int rowBase = (blockIdx.x - 1024) * 64 + waveId * 16;  // flat (b,h,q)
  const int b = rowBase >> 15;
  const int h = (rowBase >> 11) & 15;
  const int q0 = rowBase & 2047;
  const int g = lane >> 4;   // row sub-group 0..3
  const int c = lane & 15;   // float4 column within 64-dim head slice

  const fvec4 kvv = reinterpret_cast<const fvec4*>(ws + WS_KVEC + b * 1024 + h * HD_)[c];
  const float sw1 = ws[WS_SW1];
  const float Lc = ws[WS_C2 + b] + scale_b[0];

  const float* qb = query + ((size_t)(b * QLEN + q0)) * D_ + h * HD_;
  float p[4];
#pragma unroll
  for (int j = 0; j < 4; ++j) {
    const fvec4 q4 = __builtin_nontemporal_load(
        reinterpret_cast<const fvec4*>(qb + (size_t)(j * 4 + g) * D_) + c);
    p[j] = q4.x * kvv.x + q4.y * kvv.y + q4.z * kvv.z + q4.w * kvv.w;
  }
#pragma unroll
  for (int off = 1; off <= 8; off <<= 1) {
#pragma unroll
    for (int j = 0; j < 4; ++j) p[j] += __shfl_xor(p[j], off, 64);
  }
  if (c < 4) {
    const float sp = (c == 0) ? p[0] : (c == 1) ? p[1] : (c == 2) ? p[2] : p[3];
    ws[WS_L + rowBase + c * 4 + g] = sw1 * (sp * 0.125f) + Lc;
  }
}

// Kernel 3: pure attn stream. Wave owns 32 contiguous rows (same b).
__global__ __launch_bounds__(256) void attn_stream_kernel(
    const float* __restrict__ clip, const float* __restrict__ ws,
    float* __restrict__ attn) {
  const int lane = threadIdx.x & 63;
  const int gwave = (blockIdx.x * 256 + threadIdx.x) >> 6;  // 0..8191
  const int row0 = gwave * 32;
  const int b = row0 >> 15;   // 32768 rows per batch

  const fvec4 cl = reinterpret_cast<const fvec4*>(clip + b * KV_)[lane];
  const float cmax = wave_max(fmaxf(fmaxf(cl.x, cl.y), fmaxf(cl.z, cl.w)));
  const float cmin = wave_min(fminf(fminf(cl.x, cl.y), fminf(cl.z, cl.w)));

  // One coalesced 128B read covers this wave's 32 L values.
  const float Lv = ws[WS_L + row0 + (lane & 31)];

  fvec4* a4 = reinterpret_cast<fvec4*>(attn) + (size_t)row0 * 64 + lane;
#pragma unroll
  for (int i = 0; i < 32; ++i) {
    const float Ld = __builtin_amdgcn_readlane(Lv, i);  // compile-time lane
    const float m = (Ld >= 0.f) ? Ld * cmax : Ld * cmin;
    fvec4 e;
    e.x = __expf(Ld * cl.x - m);
    e.y = __expf(Ld * cl.y - m);
    e.z = __expf(Ld * cl.z - m);
    e.w = __expf(Ld * cl.w - m);
    const float den = wave_sum(e.x + e.y + e.z + e.w);
    e *= (1.0f / den);
    __builtin_nontemporal_store(e, &a4[(size_t)i * 64]);
  }
}

extern "C" void kernel_launch(void* const* d_in, const int* in_sizes, int n_in,
                              void* d_out, int out_size, void* d_ws, size_t ws_size,
                              hipStream_t stream) {
  const float* query   = (const float*)d_in[0];
  const float* key     = (const float*)d_in[1];
  const float* value   = (const float*)d_in[2];
  const float* clip    = (const float*)d_in[3];
  const float* kw      = (const float*)d_in[4];
  const float* vw      = (const float*)d_in[5];
  const float* scale_w = (const float*)d_in[6];
  const float* scale_b = (const float*)d_in[7];
  float* out  = (float*)d_out;
  float* attn = out + (size_t)B_ * QLEN * D_;   // outputs concatenated flat
  float* ws   = (float*)d_ws;

  hipLaunchKernelGGL(prep_kernel, dim3(129), dim3(256), 0, stream,
                     key, value, kw, vw, clip, scale_w, ws);
  hipLaunchKernelGGL(qdot_out_kernel, dim3(5120), dim3(256), 0, stream,
                     query, scale_b, ws, out);
  hipLaunchKernelGGL(attn_stream_kernel, dim3(2048), dim3(256), 0, stream,
                     clip, ws, attn);
}

// Round 7
// 87.428 us; speedup vs baseline: 1.0623x; 1.0623x over previous
//
#include <hip/hip_runtime.h>
#include <hip/hip_bf16.h>

// Problem constants
#define B_    8
#define QLEN  2048
#define D_    1024
#define H_    16
#define KV_   256
#define HD_   64

typedef float fvec4 __attribute__((ext_vector_type(4)));

// ws layout (float offsets):
#define WS_KVEC 0        // B x 1024
#define WS_VVEC 8192     // B x 1024
#define WS_C2   16384    // B
#define WS_SW1  16392    // 1

__device__ inline float wave_sum(float v) {
#pragma unroll
  for (int off = 32; off > 0; off >>= 1) v += __shfl_xor(v, off, 64);
  return v;
}
__device__ inline float wave_max(float v) {
#pragma unroll
  for (int off = 32; off > 0; off >>= 1) v = fmaxf(v, __shfl_xor(v, off, 64));
  return v;
}
__device__ inline float wave_min(float v) {
#pragma unroll
  for (int off = 32; off > 0; off >>= 1) v = fminf(v, __shfl_xor(v, off, 64));
  return v;
}
template <int N>
__device__ inline void multi_sum(float* v) {
#pragma unroll
  for (int off = 32; off > 0; off >>= 1) {
#pragma unroll
    for (int r = 0; r < N; ++r) v[r] += __shfl_xor(v[r], off, 64);
  }
}

// Kernel 1: Kvec/Vvec GEMVs. Weights read ONCE (8 MB) at 2048-wave
// parallelism: one wave per (sel, d-row), looping batches (b-unroll x2).
// Block 512: c2 + sw1.
__global__ __launch_bounds__(256) void prep_kernel(
    const float* __restrict__ key, const float* __restrict__ value,
    const float* __restrict__ kw, const float* __restrict__ vw,
    const float* __restrict__ clip, const float* __restrict__ scale_w,
    float* __restrict__ ws) {
  const int lane = threadIdx.x & 63;
  const int waveId = threadIdx.x >> 6;

  if (blockIdx.x == 512) {
    if (waveId != 0) return;
    const fvec4* sw4 = reinterpret_cast<const fvec4*>(scale_w);
    fvec4 a = sw4[lane];                       // scale_w[0..255]
    float s = wave_sum(a.x + a.y + a.z + a.w);
    if (lane == 0) ws[WS_SW1] = s;
    fvec4 w2 = sw4[64 + lane];                 // scale_w[256..511]
    for (int b = 0; b < B_; ++b) {
      const fvec4* c4 = reinterpret_cast<const fvec4*>(clip + b * KV_);
      fvec4 c = c4[lane];
      float p = c.x * w2.x + c.y * w2.y + c.z * w2.z + c.w * w2.w;
      p = wave_sum(p);
      if (lane == 0) ws[WS_C2 + b] = p;
    }
    return;
  }

  const int W = blockIdx.x * 4 + waveId;  // 0..2047
  const int sel = W >> 10;                // 0=K, 1=V
  const int d = W & 1023;                 // output row
  const float* Wt = sel ? vw : kw;
  const float* xsrc = sel ? value : key;
  float* outv = ws + (sel ? WS_VVEC : WS_KVEC);

  const fvec4* w4 = reinterpret_cast<const fvec4*>(Wt + (size_t)d * 1024);
  fvec4 wr[4];
#pragma unroll
  for (int i = 0; i < 4; ++i) wr[i] = w4[i * 64 + lane];

#pragma unroll
  for (int b0 = 0; b0 < B_; b0 += 2) {
    const fvec4* xa = reinterpret_cast<const fvec4*>(xsrc + b0 * 1024);
    const fvec4* xb = reinterpret_cast<const fvec4*>(xsrc + (b0 + 1) * 1024);
    float acc[2] = {0.f, 0.f};
#pragma unroll
    for (int i = 0; i < 4; ++i) {
      fvec4 x0 = xa[i * 64 + lane];
      fvec4 x1 = xb[i * 64 + lane];
      acc[0] += x0.x * wr[i].x + x0.y * wr[i].y + x0.z * wr[i].z + x0.w * wr[i].w;
      acc[1] += x1.x * wr[i].x + x1.y * wr[i].y + x1.z * wr[i].z + x1.w * wr[i].w;
    }
    multi_sum<2>(acc);
    if (lane == 0) {
      outv[b0 * 1024 + d] = acc[0];
      outv[(b0 + 1) * 1024 + d] = acc[1];
    }
  }
}

// Kernel 2 (fused): each wave owns 32 contiguous rows (same b,h).
//  - out-broadcast (8 x 1KB chunks, independent of everything but Vvec)
//  - phase 1: 32 Q.Kvec dots via 16-lane-group reduction (short prefix)
//  - phase 2: per-row softmax stream (exp, wave-reduce denom, nt store)
__global__ __launch_bounds__(256) void fused_kernel(
    const float* __restrict__ query, const float* __restrict__ clip,
    const float* __restrict__ scale_b, const float* __restrict__ ws,
    float* __restrict__ attn, float* __restrict__ out) {
  const int lane = threadIdx.x & 63;
  const int gwave = (blockIdx.x * 256 + threadIdx.x) >> 6;  // 0..8191
  const int row0 = gwave * 32;
  const int b = row0 >> 15;           // 32768 rows per batch
  const int h = (row0 >> 11) & 15;    // 2048 rows per head
  const int q0 = row0 & 2047;
  const int g = lane >> 4;            // row sub-group 0..3
  const int c = lane & 15;            // fvec4 column in 64-dim head slice

  // Out-broadcast: stores depend only on Vvec; issue first.
  {
    const fvec4* v4 = reinterpret_cast<const fvec4*>(ws + WS_VVEC);
    fvec4* o4 = reinterpret_cast<fvec4*>(out);
#pragma unroll
    for (int i = 0; i < 8; ++i) {
      const int j = (gwave * 8 + i) * 64 + lane;
      const int ob = j >> 19;          // 524288 float4 per batch
      const int d4 = j & 255;
      fvec4 v = v4[ob * 256 + d4];
      __builtin_nontemporal_store(v, &o4[j]);
    }
  }

  // Phase 1: L for this wave's 32 rows. Row i = j*4+g, q = q0+i.
  const fvec4 kvv =
      reinterpret_cast<const fvec4*>(ws + WS_KVEC + b * 1024 + h * HD_)[c];
  const float sw1 = ws[WS_SW1];
  const float Lc = ws[WS_C2 + b] + scale_b[0];
  const float* qb = query + ((size_t)(b * QLEN + q0)) * D_ + h * HD_;

  float p[8];
#pragma unroll
  for (int j = 0; j < 8; ++j) {
    const fvec4 q4 = __builtin_nontemporal_load(
        reinterpret_cast<const fvec4*>(qb + (size_t)(j * 4 + g) * D_) + c);
    p[j] = q4.x * kvv.x + q4.y * kvv.y + q4.z * kvv.z + q4.w * kvv.w;
  }
#pragma unroll
  for (int off = 1; off <= 8; off <<= 1) {
#pragma unroll
    for (int j = 0; j < 8; ++j) p[j] += __shfl_xor(p[j], off, 64);
  }
#pragma unroll
  for (int j = 0; j < 8; ++j) p[j] = sw1 * (p[j] * 0.125f) + Lc;

  const fvec4 cl = reinterpret_cast<const fvec4*>(clip + b * KV_)[lane];
  const float cmax = wave_max(fmaxf(fmaxf(cl.x, cl.y), fmaxf(cl.z, cl.w)));
  const float cmin = wave_min(fminf(fminf(cl.x, cl.y), fminf(cl.z, cl.w)));

  // Phase 2: stream 32 attn rows.
  fvec4* a4 = reinterpret_cast<fvec4*>(attn) + (size_t)row0 * 64 + lane;
#pragma unroll
  for (int i = 0; i < 32; ++i) {
    const float Ld = __builtin_amdgcn_readlane(p[i >> 2], (i & 3) << 4);
    const float m = (Ld >= 0.f) ? Ld * cmax : Ld * cmin;
    fvec4 e;
    e.x = __expf(Ld * cl.x - m);
    e.y = __expf(Ld * cl.y - m);
    e.z = __expf(Ld * cl.z - m);
    e.w = __expf(Ld * cl.w - m);
    const float den = wave_sum(e.x + e.y + e.z + e.w);
    e *= (1.0f / den);
    __builtin_nontemporal_store(e, &a4[(size_t)i * 64]);
  }
}

extern "C" void kernel_launch(void* const* d_in, const int* in_sizes, int n_in,
                              void* d_out, int out_size, void* d_ws, size_t ws_size,
                              hipStream_t stream) {
  const float* query   = (const float*)d_in[0];
  const float* key     = (const float*)d_in[1];
  const float* value   = (const float*)d_in[2];
  const float* clip    = (const float*)d_in[3];
  const float* kw      = (const float*)d_in[4];
  const float* vw      = (const float*)d_in[5];
  const float* scale_w = (const float*)d_in[6];
  const float* scale_b = (const float*)d_in[7];
  float* out  = (float*)d_out;
  float* attn = out + (size_t)B_ * QLEN * D_;   // outputs concatenated flat
  float* ws   = (float*)d_ws;

  hipLaunchKernelGGL(prep_kernel, dim3(513), dim3(256), 0, stream,
                     key, value, kw, vw, clip, scale_w, ws);
  hipLaunchKernelGGL(fused_kernel, dim3(2048), dim3(256), 0, stream,
                     query, clip, scale_b, ws, attn, out);
}

// Round 8
// 85.070 us; speedup vs baseline: 1.0917x; 1.0277x over previous
//
#include <hip/hip_runtime.h>
#include <hip/hip_bf16.h>

// Problem constants
#define B_    8
#define QLEN  2048
#define D_    1024
#define H_    16
#define KV_   256
#define HD_   64

#define NWAVE 2048          // fused kernel: 512 blocks x 4 waves
#define NSETS 4             // row-sets per wave (32 rows each)

typedef float fvec4 __attribute__((ext_vector_type(4)));

// ws layout (float offsets):
#define WS_KVEC 0        // B x 1024
#define WS_VVEC 8192     // B x 1024
#define WS_C2   16384    // B
#define WS_SW1  16392    // 1

__device__ inline float wave_sum(float v) {
#pragma unroll
  for (int off = 32; off > 0; off >>= 1) v += __shfl_xor(v, off, 64);
  return v;
}
template <int N>
__device__ inline void multi_sum(float* v) {
#pragma unroll
  for (int off = 32; off > 0; off >>= 1) {
#pragma unroll
    for (int r = 0; r < N; ++r) v[r] += __shfl_xor(v[r], off, 64);
  }
}

// Kernel 1: Kvec/Vvec GEMVs. Weights read ONCE (8 MB) at 2048-wave
// parallelism: one wave per (sel, d-row), looping batches (b-unroll x2).
// Block 512: c2 + sw1.
__global__ __launch_bounds__(256) void prep_kernel(
    const float* __restrict__ key, const float* __restrict__ value,
    const float* __restrict__ kw, const float* __restrict__ vw,
    const float* __restrict__ clip, const float* __restrict__ scale_w,
    float* __restrict__ ws) {
  const int lane = threadIdx.x & 63;
  const int waveId = threadIdx.x >> 6;

  if (blockIdx.x == 512) {
    if (waveId != 0) return;
    const fvec4* sw4 = reinterpret_cast<const fvec4*>(scale_w);
    fvec4 a = sw4[lane];                       // scale_w[0..255]
    float s = wave_sum(a.x + a.y + a.z + a.w);
    if (lane == 0) ws[WS_SW1] = s;
    fvec4 w2 = sw4[64 + lane];                 // scale_w[256..511]
    for (int b = 0; b < B_; ++b) {
      const fvec4* c4 = reinterpret_cast<const fvec4*>(clip + b * KV_);
      fvec4 c = c4[lane];
      float p = c.x * w2.x + c.y * w2.y + c.z * w2.z + c.w * w2.w;
      p = wave_sum(p);
      if (lane == 0) ws[WS_C2 + b] = p;
    }
    return;
  }

  const int W = blockIdx.x * 4 + waveId;  // 0..2047
  const int sel = W >> 10;                // 0=K, 1=V
  const int d = W & 1023;                 // output row
  const float* Wt = sel ? vw : kw;
  const float* xsrc = sel ? value : key;
  float* outv = ws + (sel ? WS_VVEC : WS_KVEC);

  const fvec4* w4 = reinterpret_cast<const fvec4*>(Wt + (size_t)d * 1024);
  fvec4 wr[4];
#pragma unroll
  for (int i = 0; i < 4; ++i) wr[i] = w4[i * 64 + lane];

#pragma unroll
  for (int b0 = 0; b0 < B_; b0 += 2) {
    const fvec4* xa = reinterpret_cast<const fvec4*>(xsrc + b0 * 1024);
    const fvec4* xb = reinterpret_cast<const fvec4*>(xsrc + (b0 + 1) * 1024);
    float acc[2] = {0.f, 0.f};
#pragma unroll
    for (int i = 0; i < 4; ++i) {
      fvec4 x0 = xa[i * 64 + lane];
      fvec4 x1 = xb[i * 64 + lane];
      acc[0] += x0.x * wr[i].x + x0.y * wr[i].y + x0.z * wr[i].z + x0.w * wr[i].w;
      acc[1] += x1.x * wr[i].x + x1.y * wr[i].y + x1.z * wr[i].z + x1.w * wr[i].w;
    }
    multi_sum<2>(acc);
    if (lane == 0) {
      outv[b0 * 1024 + d] = acc[0];
      outv[(b0 + 1) * 1024 + d] = acc[1];
    }
  }
}

// ---- fused pipelined kernel helpers ----

// Issue all loads for a row-set: 8 nt Q fvec4 per lane + Kvec slice + clip row.
__device__ __forceinline__ void load_set(
    int setId, const float* __restrict__ query, const float* __restrict__ clip,
    const float* __restrict__ ws, int lane, int g, int c,
    fvec4 qb[8], fvec4& kv, fvec4& cl) {
  const int row0 = setId * 32;
  const int b = row0 >> 15;
  const int h = (row0 >> 11) & 15;
  const int q0 = row0 & 2047;
  const float* qp = query + ((size_t)(b * QLEN + q0)) * D_ + h * HD_;
#pragma unroll
  for (int j = 0; j < 8; ++j) {
    qb[j] = __builtin_nontemporal_load(
        reinterpret_cast<const fvec4*>(qp + (size_t)(j * 4 + g) * D_) + c);
  }
  kv = reinterpret_cast<const fvec4*>(ws + WS_KVEC + b * 1024 + h * HD_)[c];
  cl = reinterpret_cast<const fvec4*>(clip + b * KV_)[lane];
}

// Process a row-set: L values, batched denominators, stream 32 attn rows
// + 8 out-broadcast chunks.
__device__ __forceinline__ void proc_set(
    int setId, const fvec4 qb[8], fvec4 kv, fvec4 cl,
    float sw1, const float* __restrict__ ws, float sb,
    float* __restrict__ attn, float* __restrict__ out, int lane) {
  const int row0 = setId * 32;
  const int b = row0 >> 15;
  const float Lc = ws[WS_C2 + b] + sb;

  // 32 dot-products via 16-lane-group reduction (4 levels).
  float p[8];
#pragma unroll
  for (int j = 0; j < 8; ++j)
    p[j] = qb[j].x * kv.x + qb[j].y * kv.y + qb[j].z * kv.z + qb[j].w * kv.w;
#pragma unroll
  for (int off = 1; off <= 8; off <<= 1) {
#pragma unroll
    for (int j = 0; j < 8; ++j) p[j] += __shfl_xor(p[j], off, 64);
  }
#pragma unroll
  for (int j = 0; j < 8; ++j) p[j] = sw1 * (p[j] * 0.125f) + Lc;

  // Row L values -> wave-uniform (SGPR via readlane). Row i = (i>>2)*4+(i&3):
  // its sum lives in lane group g=(i&3), take lane (i&3)*16, reg p[i>>2].
  float L32[32];
#pragma unroll
  for (int i = 0; i < 32; ++i)
    L32[i] = __builtin_amdgcn_readlane(p[i >> 2], (i & 3) << 4);

  // Batched denominators: lane-local 4-exp partials for all 32 rows,
  // then one 6-level multi-reduce. No max-subtraction needed:
  // |L*cl| <= |L| << 88, so exp() cannot overflow/underflow harmfully.
  float t[32];
#pragma unroll
  for (int i = 0; i < 32; ++i) {
    t[i] = __expf(L32[i] * cl.x) + __expf(L32[i] * cl.y) +
           __expf(L32[i] * cl.z) + __expf(L32[i] * cl.w);
  }
  multi_sum<32>(t);

  // Stream phase: pure VALU + stores, zero cross-lane ops.
  fvec4* a4 = reinterpret_cast<fvec4*>(attn) + (size_t)row0 * 64 + lane;
#pragma unroll
  for (int i = 0; i < 32; ++i) {
    const float rd = __builtin_amdgcn_rcpf(t[i]);
    fvec4 e;
    e.x = __expf(L32[i] * cl.x) * rd;
    e.y = __expf(L32[i] * cl.y) * rd;
    e.z = __expf(L32[i] * cl.z) * rd;
    e.w = __expf(L32[i] * cl.w) * rd;
    __builtin_nontemporal_store(e, &a4[(size_t)i * 64]);
  }

  // Out-broadcast: 8 x 1KB chunks per set.
  const fvec4* v4 = reinterpret_cast<const fvec4*>(ws + WS_VVEC);
  fvec4* o4 = reinterpret_cast<fvec4*>(out);
#pragma unroll
  for (int i = 0; i < 8; ++i) {
    const int j = (setId * 8 + i) * 64 + lane;
    const int ob = j >> 19;            // 524288 float4 per batch
    const int d4 = j & 255;
    fvec4 v = v4[ob * 256 + d4];
    __builtin_nontemporal_store(v, &o4[j]);
  }
}

// Kernel 2: software-pipelined fused kernel. Each wave handles NSETS sets of
// 32 rows; set k+1's Q loads are issued before set k's store stream, so the
// 67 MB Q read hides under the 335 MB write stream.
__global__ __launch_bounds__(256) void fused_kernel(
    const float* __restrict__ query, const float* __restrict__ clip,
    const float* __restrict__ scale_b, const float* __restrict__ ws,
    float* __restrict__ attn, float* __restrict__ out) {
  const int lane = threadIdx.x & 63;
  const int gwave = (blockIdx.x * 256 + threadIdx.x) >> 6;  // 0..NWAVE-1
  const int g = lane >> 4;
  const int c = lane & 15;
  const float sw1 = ws[WS_SW1];
  const float sb = scale_b[0];

  fvec4 qA[8], qB[8], kvA, kvB, clA, clB;

  load_set(0 * NWAVE + gwave, query, clip, ws, lane, g, c, qA, kvA, clA);

  load_set(1 * NWAVE + gwave, query, clip, ws, lane, g, c, qB, kvB, clB);
  proc_set(0 * NWAVE + gwave, qA, kvA, clA, sw1, ws, sb, attn, out, lane);

  load_set(2 * NWAVE + gwave, query, clip, ws, lane, g, c, qA, kvA, clA);
  proc_set(1 * NWAVE + gwave, qB, kvB, clB, sw1, ws, sb, attn, out, lane);

  load_set(3 * NWAVE + gwave, query, clip, ws, lane, g, c, qB, kvB, clB);
  proc_set(2 * NWAVE + gwave, qA, kvA, clA, sw1, ws, sb, attn, out, lane);

  proc_set(3 * NWAVE + gwave, qB, kvB, clB, sw1, ws, sb, attn, out, lane);
}

extern "C" void kernel_launch(void* const* d_in, const int* in_sizes, int n_in,
                              void* d_out, int out_size, void* d_ws, size_t ws_size,
                              hipStream_t stream) {
  const float* query   = (const float*)d_in[0];
  const float* key     = (const float*)d_in[1];
  const float* value   = (const float*)d_in[2];
  const float* clip    = (const float*)d_in[3];
  const float* kw      = (const float*)d_in[4];
  const float* vw      = (const float*)d_in[5];
  const float* scale_w = (const float*)d_in[6];
  const float* scale_b = (const float*)d_in[7];
  float* out  = (float*)d_out;
  float* attn = out + (size_t)B_ * QLEN * D_;   // outputs concatenated flat
  float* ws   = (float*)d_ws;

  hipLaunchKernelGGL(prep_kernel, dim3(513), dim3(256), 0, stream,
                     key, value, kw, vw, clip, scale_w, ws);
  hipLaunchKernelGGL(fused_kernel, dim3(NWAVE / 4), dim3(256), 0, stream,
                     query, clip, scale_b, ws, attn, out);
}

// Round 10
// 81.102 us; speedup vs baseline: 1.1451x; 1.0489x over previous
//
#include <hip/hip_runtime.h>
#include <hip/hip_bf16.h>

// Problem constants
#define B_    8
#define QLEN  2048
#define D_    1024
#define H_    16
#define KV_   256
#define HD_   64

typedef float fvec4 __attribute__((ext_vector_type(4)));

// ws layout (float offsets) — total 278544 floats = 1.114 MB (R5-proven size):
#define WS_KVEC 0        // B x 1024
#define WS_VVEC 8192     // B x 1024
#define WS_C2   16384    // B
#define WS_SW1  16392    // 1
#define WS_L    16400    // 256K floats: L[b,h,q]

__device__ inline float wave_sum(float v) {
#pragma unroll
  for (int off = 32; off > 0; off >>= 1) v += __shfl_xor(v, off, 64);
  return v;
}
template <int N>
__device__ inline void multi_sum(float* v) {
#pragma unroll
  for (int off = 32; off > 0; off >>= 1) {
#pragma unroll
    for (int r = 0; r < N; ++r) v[r] += __shfl_xor(v[r], off, 64);
  }
}

// Kernel 1: Kvec/Vvec GEMVs. Weights read ONCE (8 MB) at 2048-wave
// parallelism: one wave per (sel, d-row), looping batches (b-unroll x2).
// Block 512: c2 + sw1.  (R8-validated)
__global__ __launch_bounds__(256) void prep_kernel(
    const float* __restrict__ key, const float* __restrict__ value,
    const float* __restrict__ kw, const float* __restrict__ vw,
    const float* __restrict__ clip, const float* __restrict__ scale_w,
    float* __restrict__ ws) {
  const int lane = threadIdx.x & 63;
  const int waveId = threadIdx.x >> 6;

  if (blockIdx.x == 512) {
    if (waveId != 0) return;
    const fvec4* sw4 = reinterpret_cast<const fvec4*>(scale_w);
    fvec4 a = sw4[lane];                       // scale_w[0..255]
    float s = wave_sum(a.x + a.y + a.z + a.w);
    if (lane == 0) ws[WS_SW1] = s;
    fvec4 w2 = sw4[64 + lane];                 // scale_w[256..511]
    for (int b = 0; b < B_; ++b) {
      const fvec4* c4 = reinterpret_cast<const fvec4*>(clip + b * KV_);
      fvec4 c = c4[lane];
      float p = c.x * w2.x + c.y * w2.y + c.z * w2.z + c.w * w2.w;
      p = wave_sum(p);
      if (lane == 0) ws[WS_C2 + b] = p;
    }
    return;
  }

  const int W = blockIdx.x * 4 + waveId;  // 0..2047
  const int sel = W >> 10;                // 0=K, 1=V
  const int d = W & 1023;                 // output row
  const float* Wt = sel ? vw : kw;
  const float* xsrc = sel ? value : key;
  float* outv = ws + (sel ? WS_VVEC : WS_KVEC);

  const fvec4* w4 = reinterpret_cast<const fvec4*>(Wt + (size_t)d * 1024);
  fvec4 wr[4];
#pragma unroll
  for (int i = 0; i < 4; ++i) wr[i] = w4[i * 64 + lane];

#pragma unroll
  for (int b0 = 0; b0 < B_; b0 += 2) {
    const fvec4* xa = reinterpret_cast<const fvec4*>(xsrc + b0 * 1024);
    const fvec4* xb = reinterpret_cast<const fvec4*>(xsrc + (b0 + 1) * 1024);
    float acc[2] = {0.f, 0.f};
#pragma unroll
    for (int i = 0; i < 4; ++i) {
      fvec4 x0 = xa[i * 64 + lane];
      fvec4 x1 = xb[i * 64 + lane];
      acc[0] += x0.x * wr[i].x + x0.y * wr[i].y + x0.z * wr[i].z + x0.w * wr[i].w;
      acc[1] += x1.x * wr[i].x + x1.y * wr[i].y + x1.z * wr[i].z + x1.w * wr[i].w;
    }
    multi_sum<2>(acc);
    if (lane == 0) {
      outv[b0 * 1024 + d] = acc[0];
      outv[(b0 + 1) * 1024 + d] = acc[1];
    }
  }
}

// Kernel 2: L[row] = sw1 * dot(Q_row, Kvec_head)/8 + c2[b] + scale_b.
// Wave owns 16 rows; float4 Q loads; 16-lane group reductions. (R5-validated)
__global__ __launch_bounds__(256) void qdot_kernel(
    const float* __restrict__ query, const float* __restrict__ scale_b,
    float* __restrict__ ws) {
  const int lane = threadIdx.x & 63;
  const int waveId = threadIdx.x >> 6;
  const int rowBase = blockIdx.x * 64 + waveId * 16;  // flat (b,h,q)
  const int b = rowBase >> 15;
  const int h = (rowBase >> 11) & 15;
  const int q0 = rowBase & 2047;
  const int g = lane >> 4;   // row sub-group 0..3
  const int c = lane & 15;   // float4 column within 64-dim head slice

  const fvec4 kvv = reinterpret_cast<const fvec4*>(ws + WS_KVEC + b * 1024 + h * HD_)[c];
  const float sw1 = ws[WS_SW1];
  const float Lc = ws[WS_C2 + b] + scale_b[0];

  const float* qb = query + ((size_t)(b * QLEN + q0)) * D_ + h * HD_;
  float p[4];
#pragma unroll
  for (int j = 0; j < 4; ++j) {
    const fvec4 q4 = __builtin_nontemporal_load(
        reinterpret_cast<const fvec4*>(qb + (size_t)(j * 4 + g) * D_) + c);
    p[j] = q4.x * kvv.x + q4.y * kvv.y + q4.z * kvv.z + q4.w * kvv.w;
  }
#pragma unroll
  for (int off = 1; off <= 8; off <<= 1) {
#pragma unroll
    for (int j = 0; j < 4; ++j) p[j] += __shfl_xor(p[j], off, 64);
  }
  if (c < 4) {
    const float sp = (c == 0) ? p[0] : (c == 1) ? p[1] : (c == 2) ? p[2] : p[3];
    ws[WS_L + rowBase + c * 4 + g] = sw1 * (sp * 0.125f) + Lc;
  }
}

// Kernel 3: store stream with BATCHED denominators. Wave owns 32 rows:
// one upfront block (128 exps + multi_sum<32>, 6 dependent levels) computes
// all denominators; the store loop is then pure VALU + nt stores.
__global__ __launch_bounds__(256) void attn_stream_kernel(
    const float* __restrict__ clip, const float* __restrict__ ws,
    float* __restrict__ attn, float* __restrict__ out) {
  const int lane = threadIdx.x & 63;
  const int gwave = (blockIdx.x * 256 + threadIdx.x) >> 6;  // 0..8191
  const int row0 = gwave * 32;
  const int b = row0 >> 15;   // 32768 rows per batch

  const fvec4 cl = reinterpret_cast<const fvec4*>(clip + b * KV_)[lane];
  // One coalesced 128B read covers this wave's 32 L values.
  const float Lv = ws[WS_L + row0 + (lane & 31)];

  // Batched denominators: no max subtraction (|L| < ~60 << 88, no overflow;
  // positive-term sums are well-conditioned).  R8-validated numerics.
  float t[32];
#pragma unroll
  for (int i = 0; i < 32; ++i) {
    const float Ld = __builtin_amdgcn_readlane(Lv, i);
    t[i] = __expf(Ld * cl.x) + __expf(Ld * cl.y) +
           __expf(Ld * cl.z) + __expf(Ld * cl.w);
  }
  multi_sum<32>(t);

  // Pure store stream: zero cross-lane ops between stores.
  fvec4* a4 = reinterpret_cast<fvec4*>(attn) + (size_t)row0 * 64 + lane;
#pragma unroll
  for (int i = 0; i < 32; ++i) {
    const float Ld = __builtin_amdgcn_readlane(Lv, i);
    const float rd = __builtin_amdgcn_rcpf(t[i]);
    fvec4 e;
    e.x = __expf(Ld * cl.x) * rd;
    e.y = __expf(Ld * cl.y) * rd;
    e.z = __expf(Ld * cl.z) * rd;
    e.w = __expf(Ld * cl.w) * rd;
    __builtin_nontemporal_store(e, &a4[(size_t)i * 64]);
  }

  // out broadcast: 65536 chunks of 1KB; this wave does 8.
  const fvec4* v4 = reinterpret_cast<const fvec4*>(ws + WS_VVEC);
  fvec4* o4 = reinterpret_cast<fvec4*>(out);
#pragma unroll
  for (int i = 0; i < 8; ++i) {
    const int j = (gwave * 8 + i) * 64 + lane;  // float4 index
    const int ob = j >> 19;                     // 524288 float4 per batch
    const int d4 = j & 255;
    fvec4 v = v4[ob * 256 + d4];
    __builtin_nontemporal_store(v, &o4[j]);
  }
}

extern "C" void kernel_launch(void* const* d_in, const int* in_sizes, int n_in,
                              void* d_out, int out_size, void* d_ws, size_t ws_size,
                              hipStream_t stream) {
  const float* query   = (const float*)d_in[0];
  const float* key     = (const float*)d_in[1];
  const float* value   = (const float*)d_in[2];
  const float* clip    = (const float*)d_in[3];
  const float* kw      = (const float*)d_in[4];
  const float* vw      = (const float*)d_in[5];
  const float* scale_w = (const float*)d_in[6];
  const float* scale_b = (const float*)d_in[7];
  float* out  = (float*)d_out;
  float* attn = out + (size_t)B_ * QLEN * D_;   // outputs concatenated flat
  float* ws   = (float*)d_ws;

  hipLaunchKernelGGL(prep_kernel, dim3(513), dim3(256), 0, stream,
                     key, value, kw, vw, clip, scale_w, ws);
  hipLaunchKernelGGL(qdot_kernel, dim3(4096), dim3(256), 0, stream,
                     query, scale_b, ws);
  hipLaunchKernelGGL(attn_stream_kernel, dim3(2048), dim3(256), 0, stream,
                     clip, ws, attn, out);
}